// Round 3
// baseline (5045.325 us; speedup 1.0000x reference)
//
#include <hip/hip_runtime.h>

#define BB 64
#define TT 512
#define II 256
#define HH 512
#define OO 256

typedef _Float16 f16;
typedef _Float16 half8 __attribute__((ext_vector_type(8)));
typedef _Float16 half4 __attribute__((ext_vector_type(4)));
typedef float f32x4 __attribute__((ext_vector_type(4)));

// ---------------- prep: transpose x to time-major fp16, zero counters ----------------
__global__ void prep_x(const float* __restrict__ x, f16* __restrict__ xt,
                       unsigned* __restrict__ cnt) {
  size_t tid = (size_t)blockIdx.x * blockDim.x + threadIdx.x;
  if (tid < 256) cnt[tid] = 0;
  size_t stride = (size_t)gridDim.x * blockDim.x;
  size_t nv = (size_t)TT * BB * II / 4;
  for (size_t v = tid; v < nv; v += stride) {
    size_t i = v * 4;
    size_t t = i >> 14;        // / (BB*II)
    size_t rem = i & 16383;
    size_t b = rem >> 8;       // / II
    size_t ii = rem & 255;
    float4 f = *(const float4*)(x + b * (size_t)(TT * II) + t * II + ii);
    half4 h;
    h.x = (f16)f.x; h.y = (f16)f.y; h.z = (f16)f.z; h.w = (f16)f.w;
    *(half4*)(xt + i) = h;
  }
}

// ---------------- prep: weights fp32 -> fp16 (layout kept [out][in]), bias sums ----------------
__global__ void prep_w(const float* __restrict__ wih0, const float* __restrict__ whh0,
                       const float* __restrict__ wih1, const float* __restrict__ whh1,
                       const float* __restrict__ bih0, const float* __restrict__ bhh0,
                       const float* __restrict__ bih1, const float* __restrict__ bhh1,
                       f16* __restrict__ o0, f16* __restrict__ o1,
                       f16* __restrict__ o2, f16* __restrict__ o3,
                       float* __restrict__ bs0, float* __restrict__ bs1) {
  const size_t n0 = (size_t)HH * II, n1 = (size_t)HH * HH;
  const size_t total = n0 + 3 * n1 + 2 * HH;
  size_t stride = (size_t)gridDim.x * blockDim.x;
  for (size_t i = (size_t)blockIdx.x * blockDim.x + threadIdx.x; i < total; i += stride) {
    size_t j = i;
    if (j < n0) { o0[j] = (f16)wih0[j]; continue; } j -= n0;
    if (j < n1) { o1[j] = (f16)whh0[j]; continue; } j -= n1;
    if (j < n1) { o2[j] = (f16)wih1[j]; continue; } j -= n1;
    if (j < n1) { o3[j] = (f16)whh1[j]; continue; } j -= n1;
    if (j < HH) { bs0[j] = bih0[j] + bhh0[j]; continue; } j -= HH;
    bs1[j] = bih1[j] + bhh1[j];
  }
}

// ---- intra-cluster wait: all 32 counters of `base` >= target (relaxed poll + acq fence) ----
__device__ __forceinline__ void waitc(const unsigned* base, unsigned target,
                                      int lane, long* budget) {
  const unsigned* p = base + (lane & 31);
  for (;;) {
    unsigned v = __hip_atomic_load(p, __ATOMIC_RELAXED, __HIP_MEMORY_SCOPE_AGENT);
    if (!__any((int)(v < target))) break;
    if (--(*budget) < 0) break;  // safety: never hang forever
  }
  __builtin_amdgcn_fence(__ATOMIC_ACQUIRE, "agent");
}

__device__ __forceinline__ void publish(unsigned* p, unsigned v, int lane) {
  if (lane == 0)
    __hip_atomic_store(p, v, __ATOMIC_RELEASE, __HIP_MEMORY_SCOPE_AGENT);
}

// ---- pipelined 2-layer RNN: 256 waves = 2 layers x 4 batch-clusters x 32 H-slices ----
__global__ __launch_bounds__(64, 1) void rnn_seq(
    const f16* __restrict__ xt, f16* __restrict__ ys0, f16* __restrict__ h1h,
    float* __restrict__ h1fin,
    const f16* __restrict__ wih0, const f16* __restrict__ whh0,
    const f16* __restrict__ wih1, const f16* __restrict__ whh1,
    const float* __restrict__ bs0, const float* __restrict__ bs1,
    const float* __restrict__ wfc, const float* __restrict__ bfc,
    float* __restrict__ out, unsigned* __restrict__ cnt) {
  const int wg = blockIdx.x;        // 0..255
  const int layer = wg >> 7;        // 0/1
  const int c = (wg >> 5) & 3;      // batch cluster (rows c*16..+15)
  const int s = wg & 31;            // H-slice (cols s*16..+15)
  const int lane = threadIdx.x;
  const int fr = lane & 15;
  const int kg = lane >> 4;         // 0..3
  unsigned* l0base = cnt + c * 32;
  unsigned* l1base = cnt + 128 + c * 32;
  unsigned* mycnt = cnt + wg;
  long budget = 20000000;

  if (layer == 0) {
    // =============== layer 0 ===============
    half8 wbi[8], wbh[16];
    {
      const f16* wi = wih0 + (size_t)(s * 16 + fr) * II + kg * 8;
#pragma unroll
      for (int kf = 0; kf < 8; ++kf) wbi[kf] = *(const half8*)(wi + kf * 32);
      const f16* wh = whh0 + (size_t)(s * 16 + fr) * HH + kg * 8;
#pragma unroll
      for (int kf = 0; kf < 16; ++kf) wbh[kf] = *(const half8*)(wh + kf * 32);
    }
    const float bias = bs0[s * 16 + fr];
    // input projection for t=0 (off critical path thereafter)
    f32x4 pacc[4] = {{0,0,0,0},{0,0,0,0},{0,0,0,0},{0,0,0,0}};
    {
      const f16* xa = xt + ((size_t)0 * BB + c * 16 + fr) * II + kg * 8;
#pragma unroll
      for (int kf = 0; kf < 8; ++kf) {
        half8 a = *(const half8*)(xa + kf * 32);
        pacc[kf & 3] = __builtin_amdgcn_mfma_f32_16x16x32_f16(a, wbi[kf], pacc[kf & 3], 0, 0, 0);
      }
    }
    for (int t = 0; t < TT; ++t) {
      f32x4 a0 = pacc[0], a1 = pacc[1], a2 = pacc[2], a3 = pacc[3];
      if (t > 0) {
        waitc(l0base, (unsigned)t, lane, &budget);   // h0[t-1] fully written
        const f16* ha = ys0 + ((size_t)(t - 1) * BB + c * 16 + fr) * HH + kg * 8;
#pragma unroll
        for (int kf = 0; kf < 16; kf += 4) {
          a0 = __builtin_amdgcn_mfma_f32_16x16x32_f16(*(const half8*)(ha + (kf + 0) * 32), wbh[kf + 0], a0, 0, 0, 0);
          a1 = __builtin_amdgcn_mfma_f32_16x16x32_f16(*(const half8*)(ha + (kf + 1) * 32), wbh[kf + 1], a1, 0, 0, 0);
          a2 = __builtin_amdgcn_mfma_f32_16x16x32_f16(*(const half8*)(ha + (kf + 2) * 32), wbh[kf + 2], a2, 0, 0, 0);
          a3 = __builtin_amdgcn_mfma_f32_16x16x32_f16(*(const half8*)(ha + (kf + 3) * 32), wbh[kf + 3], a3, 0, 0, 0);
        }
      }
      f32x4 acc = (a0 + a1) + (a2 + a3);
      // D[m=(kg*4+r)][n=fr] -> ys0[t][c*16+m][s*16+n]
      f16* yo = ys0 + ((size_t)t * BB + c * 16 + kg * 4) * HH + s * 16 + fr;
#pragma unroll
      for (int r = 0; r < 4; ++r) yo[(size_t)r * HH] = (f16)tanhf(acc[r] + bias);
      publish(mycnt, (unsigned)(t + 1), lane);
      // off critical path: input projection for t+1
      if (t + 1 < TT) {
#pragma unroll
        for (int q = 0; q < 4; ++q) pacc[q] = (f32x4){0, 0, 0, 0};
        const f16* xa = xt + ((size_t)(t + 1) * BB + c * 16 + fr) * II + kg * 8;
#pragma unroll
        for (int kf = 0; kf < 8; ++kf) {
          half8 a = *(const half8*)(xa + kf * 32);
          pacc[kf & 3] = __builtin_amdgcn_mfma_f32_16x16x32_f16(a, wbi[kf], pacc[kf & 3], 0, 0, 0);
        }
      }
    }
  } else {
    // =============== layer 1 ===============
    half8 wbi[16], wbh[16];
    {
      const f16* wi = wih1 + (size_t)(s * 16 + fr) * HH + kg * 8;
#pragma unroll
      for (int kf = 0; kf < 16; ++kf) wbi[kf] = *(const half8*)(wi + kf * 32);
      const f16* wh = whh1 + (size_t)(s * 16 + fr) * HH + kg * 8;
#pragma unroll
      for (int kf = 0; kf < 16; ++kf) wbh[kf] = *(const half8*)(wh + kf * 32);
    }
    const float bias = bs1[s * 16 + fr];
    for (int t = 0; t < TT; ++t) {
      waitc(l0base, (unsigned)(t + 1), lane, &budget);  // ys0[t] ready
      f32x4 a0 = {0,0,0,0}, a1 = {0,0,0,0}, a2 = {0,0,0,0}, a3 = {0,0,0,0};
      const f16* pa = ys0 + ((size_t)t * BB + c * 16 + fr) * HH + kg * 8;
#pragma unroll
      for (int kf = 0; kf < 16; kf += 4) {
        a0 = __builtin_amdgcn_mfma_f32_16x16x32_f16(*(const half8*)(pa + (kf + 0) * 32), wbi[kf + 0], a0, 0, 0, 0);
        a1 = __builtin_amdgcn_mfma_f32_16x16x32_f16(*(const half8*)(pa + (kf + 1) * 32), wbi[kf + 1], a1, 0, 0, 0);
        a2 = __builtin_amdgcn_mfma_f32_16x16x32_f16(*(const half8*)(pa + (kf + 2) * 32), wbi[kf + 2], a2, 0, 0, 0);
        a3 = __builtin_amdgcn_mfma_f32_16x16x32_f16(*(const half8*)(pa + (kf + 3) * 32), wbi[kf + 3], a3, 0, 0, 0);
      }
      if (t > 0) {
        waitc(l1base, (unsigned)t, lane, &budget);      // h1[t-1] fully written
        const f16* ha = h1h + ((size_t)(t - 1) * BB + c * 16 + fr) * HH + kg * 8;
#pragma unroll
        for (int kf = 0; kf < 16; kf += 4) {
          a0 = __builtin_amdgcn_mfma_f32_16x16x32_f16(*(const half8*)(ha + (kf + 0) * 32), wbh[kf + 0], a0, 0, 0, 0);
          a1 = __builtin_amdgcn_mfma_f32_16x16x32_f16(*(const half8*)(ha + (kf + 1) * 32), wbh[kf + 1], a1, 0, 0, 0);
          a2 = __builtin_amdgcn_mfma_f32_16x16x32_f16(*(const half8*)(ha + (kf + 2) * 32), wbh[kf + 2], a2, 0, 0, 0);
          a3 = __builtin_amdgcn_mfma_f32_16x16x32_f16(*(const half8*)(ha + (kf + 3) * 32), wbh[kf + 3], a3, 0, 0, 0);
        }
      }
      f32x4 acc = (a0 + a1) + (a2 + a3);
      f16* yo = h1h + ((size_t)t * BB + c * 16 + kg * 4) * HH + s * 16 + fr;
      if (t == TT - 1) {
        float* fo = h1fin + (size_t)(c * 16 + kg * 4) * HH + s * 16 + fr;
#pragma unroll
        for (int r = 0; r < 4; ++r) {
          float v = tanhf(acc[r] + bias);
          yo[(size_t)r * HH] = (f16)v;
          fo[(size_t)r * HH] = v;
        }
      } else {
#pragma unroll
        for (int r = 0; r < 4; ++r) yo[(size_t)r * HH] = (f16)tanhf(acc[r] + bias);
      }
      publish(mycnt, (unsigned)(t + 1), lane);
    }
    // =============== final FC: out = h1_last @ W_fc^T + b_fc (fp32) ===============
    waitc(l1base, (unsigned)TT, lane, &budget);
    const int row = c * 16 + fr;          // batch row
    const int col0 = s * 8 + kg * 2;      // two output cols per lane
    float r0 = bfc[col0], r1 = bfc[col0 + 1];
    const float4* hv = (const float4*)(h1fin + (size_t)row * HH);
    const float4* w0 = (const float4*)(wfc + (size_t)col0 * HH);
    const float4* w1 = (const float4*)(wfc + (size_t)(col0 + 1) * HH);
    for (int k = 0; k < HH / 4; ++k) {
      float4 h = hv[k], u = w0[k], v = w1[k];
      r0 += h.x * u.x + h.y * u.y + h.z * u.z + h.w * u.w;
      r1 += h.x * v.x + h.y * v.y + h.z * v.z + h.w * v.w;
    }
    out[(size_t)row * OO + col0] = r0;
    out[(size_t)row * OO + col0 + 1] = r1;
  }
}

extern "C" void kernel_launch(void* const* d_in, const int* in_sizes, int n_in,
                              void* d_out, int out_size, void* d_ws, size_t ws_size,
                              hipStream_t stream) {
  const float* x    = (const float*)d_in[0];
  const float* wih0 = (const float*)d_in[1];
  const float* whh0 = (const float*)d_in[2];
  const float* bih0 = (const float*)d_in[3];
  const float* bhh0 = (const float*)d_in[4];
  const float* wih1 = (const float*)d_in[5];
  const float* whh1 = (const float*)d_in[6];
  const float* bih1 = (const float*)d_in[7];
  const float* bhh1 = (const float*)d_in[8];
  const float* wfc  = (const float*)d_in[9];
  const float* bfc  = (const float*)d_in[10];
  float* out = (float*)d_out;

  char* base = (char*)d_ws;
  size_t off = 0;
  auto take = [&](size_t bytes) {
    char* r = base + off;
    off = (off + bytes + 255) & ~(size_t)255;
    return r;
  };
  f16* xt      = (f16*)take((size_t)TT * BB * II * 2);   // 16.8 MB
  f16* ys0     = (f16*)take((size_t)TT * BB * HH * 2);   // 33.6 MB
  f16* h1h     = (f16*)take((size_t)TT * BB * HH * 2);   // 33.6 MB
  float* h1fin = (float*)take((size_t)BB * HH * 4);
  f16* fwih0   = (f16*)take((size_t)HH * II * 2);
  f16* fwhh0   = (f16*)take((size_t)HH * HH * 2);
  f16* fwih1   = (f16*)take((size_t)HH * HH * 2);
  f16* fwhh1   = (f16*)take((size_t)HH * HH * 2);
  float* bs0   = (float*)take(HH * 4);
  float* bs1   = (float*)take(HH * 4);
  unsigned* cnt = (unsigned*)take(256 * 4);
  (void)ws_size; (void)in_sizes; (void)n_in; (void)out_size;

  prep_x<<<dim3(1024), dim3(256), 0, stream>>>(x, xt, cnt);
  prep_w<<<dim3(512), dim3(256), 0, stream>>>(wih0, whh0, wih1, whh1,
                                              bih0, bhh0, bih1, bhh1,
                                              fwih0, fwhh0, fwih1, fwhh1, bs0, bs1);

  void* args[] = {(void*)&xt, (void*)&ys0, (void*)&h1h, (void*)&h1fin,
                  (void*)&fwih0, (void*)&fwhh0, (void*)&fwih1, (void*)&fwhh1,
                  (void*)&bs0, (void*)&bs1, (void*)&wfc, (void*)&bfc,
                  (void*)&out, (void*)&cnt};
  hipError_t err = hipLaunchCooperativeKernel((const void*)rnn_seq, dim3(256), dim3(64),
                                              args, 0, stream);
  (void)err;
}

// Round 5
// 2079.920 us; speedup vs baseline: 2.4257x; 2.4257x over previous
//
#include <hip/hip_runtime.h>

#define BB 64
#define TT 512
#define II 256
#define HH 512
#define OO 256

typedef _Float16 f16;
typedef _Float16 half8 __attribute__((ext_vector_type(8)));
typedef _Float16 half4 __attribute__((ext_vector_type(4)));
typedef float f32x4 __attribute__((ext_vector_type(4)));
typedef unsigned long long u64;

#define SENT 0x7C017C017C017C01ull   // 4x f16 NaN — tanh output can never equal this

union U16 { u64 q[2]; half8 h; };

__device__ __forceinline__ u64 llc_load(const f16* p) {
  return __hip_atomic_load((const u64*)p, __ATOMIC_RELAXED, __HIP_MEMORY_SCOPE_SYSTEM);
}
__device__ __forceinline__ void llc_store(f16* p, u64 v) {
  __hip_atomic_store((u64*)p, v, __ATOMIC_RELAXED, __HIP_MEMORY_SCOPE_SYSTEM);
}

// ---------------- prep: fill ys0+h1h with sentinel ----------------
__global__ void prep_sent(u64* __restrict__ dst, size_t n) {
  size_t tid = (size_t)blockIdx.x * blockDim.x + threadIdx.x;
  size_t stride = (size_t)gridDim.x * blockDim.x;
  for (size_t i = tid; i < n; i += stride) dst[i] = SENT;
}

// ---------------- prep: transpose x to time-major fp16 ----------------
__global__ void prep_x(const float* __restrict__ x, f16* __restrict__ xt) {
  size_t tid = (size_t)blockIdx.x * blockDim.x + threadIdx.x;
  size_t stride = (size_t)gridDim.x * blockDim.x;
  size_t nv = (size_t)TT * BB * II / 4;
  for (size_t v = tid; v < nv; v += stride) {
    size_t i = v * 4;
    size_t t = i >> 14;        // / (BB*II)
    size_t rem = i & 16383;
    size_t b = rem >> 8;       // / II
    size_t ii = rem & 255;
    float4 f = *(const float4*)(x + b * (size_t)(TT * II) + t * II + ii);
    half4 h;
    h.x = (f16)f.x; h.y = (f16)f.y; h.z = (f16)f.z; h.w = (f16)f.w;
    *(half4*)(xt + i) = h;
  }
}

// ---------------- prep: weights fp32 -> fp16, bias sums ----------------
__global__ void prep_w(const float* __restrict__ wih0, const float* __restrict__ whh0,
                       const float* __restrict__ wih1, const float* __restrict__ whh1,
                       const float* __restrict__ bih0, const float* __restrict__ bhh0,
                       const float* __restrict__ bih1, const float* __restrict__ bhh1,
                       f16* __restrict__ o0, f16* __restrict__ o1,
                       f16* __restrict__ o2, f16* __restrict__ o3,
                       float* __restrict__ bs0, float* __restrict__ bs1) {
  const size_t n0 = (size_t)HH * II, n1 = (size_t)HH * HH;
  const size_t total = n0 + 3 * n1 + 2 * HH;
  size_t stride = (size_t)gridDim.x * blockDim.x;
  for (size_t i = (size_t)blockIdx.x * blockDim.x + threadIdx.x; i < total; i += stride) {
    size_t j = i;
    if (j < n0) { o0[j] = (f16)wih0[j]; continue; } j -= n0;
    if (j < n1) { o1[j] = (f16)whh0[j]; continue; } j -= n1;
    if (j < n1) { o2[j] = (f16)wih1[j]; continue; } j -= n1;
    if (j < n1) { o3[j] = (f16)whh1[j]; continue; } j -= n1;
    if (j < HH) { bs0[j] = bih0[j] + bhh0[j]; continue; } j -= HH;
    bs1[j] = bih1[j] + bhh1[j];
  }
}

// ---- validated load: 16 half8 A-fragments (32 u64) from LLC; retry until no sentinel ----
__device__ __forceinline__ void load_valid16(const f16* base, u64* q) {
  for (int iter = 0; iter < 400000; ++iter) {
#pragma unroll
    for (int kf = 0; kf < 16; ++kf) {
      q[2 * kf]     = llc_load(base + kf * 32);
      q[2 * kf + 1] = llc_load(base + kf * 32 + 4);
    }
    int ok = 1;
#pragma unroll
    for (int i = 0; i < 32; ++i) ok &= (q[i] != SENT);
    if (__all(ok)) return;
  }
}

// ---- fence-free pipelined 2-layer RNN: 128 waves = 2 layers x 4 clusters x 16 slices ----
// Plain launch (no cooperative API): 128 one-wave blocks always co-resident on 256 CUs.
__global__ __launch_bounds__(64, 1) void rnn_seq(
    const f16* __restrict__ xt, f16* __restrict__ ys0, f16* __restrict__ h1h,
    const f16* __restrict__ wih0, const f16* __restrict__ whh0,
    const f16* __restrict__ wih1, const f16* __restrict__ whh1,
    const float* __restrict__ bs0, const float* __restrict__ bs1,
    const float* __restrict__ wfc, const float* __restrict__ bfc,
    float* __restrict__ out) {
  const int wg = blockIdx.x;        // 0..127
  const int layer = wg >> 6;        // 0/1
  const int c = (wg >> 4) & 3;      // batch cluster (rows c*16..+15)
  const int s = wg & 15;            // H-slice (cols s*32..+31)
  const int lane = threadIdx.x;
  const int fr = lane & 15;
  const int kg = lane >> 4;         // 0..3
  const int n0 = s * 32;

  __shared__ f16 tile[16 * 32];     // one wave's 16x32 output tile (1 KB)

  if (layer == 0) {
    // =============== layer 0 ===============
    half8 wbi[2][8], wbh[2][16];
#pragma unroll
    for (int j = 0; j < 2; ++j) {
      const f16* wi = wih0 + (size_t)(n0 + j * 16 + fr) * II + kg * 8;
#pragma unroll
      for (int kf = 0; kf < 8; ++kf) wbi[j][kf] = *(const half8*)(wi + kf * 32);
      const f16* wh = whh0 + (size_t)(n0 + j * 16 + fr) * HH + kg * 8;
#pragma unroll
      for (int kf = 0; kf < 16; ++kf) wbh[j][kf] = *(const half8*)(wh + kf * 32);
    }
    const float bias[2] = {bs0[n0 + fr], bs0[n0 + 16 + fr]};
    // x-projection for t=0
    f32x4 pacc[2][2] = {{{0,0,0,0},{0,0,0,0}},{{0,0,0,0},{0,0,0,0}}};
    {
      const f16* xa = xt + ((size_t)0 * BB + c * 16 + fr) * II + kg * 8;
#pragma unroll
      for (int kf = 0; kf < 8; ++kf) {
        half8 a = *(const half8*)(xa + kf * 32);
        pacc[0][kf & 1] = __builtin_amdgcn_mfma_f32_16x16x32_f16(a, wbi[0][kf], pacc[0][kf & 1], 0, 0, 0);
        pacc[1][kf & 1] = __builtin_amdgcn_mfma_f32_16x16x32_f16(a, wbi[1][kf], pacc[1][kf & 1], 0, 0, 0);
      }
    }
    for (int t = 0; t < TT; ++t) {
      f32x4 acc[2][2];
#pragma unroll
      for (int j = 0; j < 2; ++j) { acc[j][0] = pacc[j][0]; acc[j][1] = pacc[j][1]; }
      if (t > 0) {
        u64 q[32];
        load_valid16(ys0 + ((size_t)(t - 1) * BB + c * 16 + fr) * HH + kg * 8, q);
#pragma unroll
        for (int kf = 0; kf < 16; ++kf) {
          U16 u; u.q[0] = q[2 * kf]; u.q[1] = q[2 * kf + 1];
          acc[0][kf & 1] = __builtin_amdgcn_mfma_f32_16x16x32_f16(u.h, wbh[0][kf], acc[0][kf & 1], 0, 0, 0);
          acc[1][kf & 1] = __builtin_amdgcn_mfma_f32_16x16x32_f16(u.h, wbh[1][kf], acc[1][kf & 1], 0, 0, 0);
        }
      }
      // tanh -> LDS transpose -> 2 contiguous u64 stores per lane
#pragma unroll
      for (int j = 0; j < 2; ++j)
#pragma unroll
        for (int r = 0; r < 4; ++r)
          tile[(kg * 4 + r) * 32 + j * 16 + fr] =
              (f16)tanhf(acc[j][0][r] + acc[j][1][r] + bias[j]);
      {
        U16 w; w.h = *(const half8*)(tile + lane * 8);
        f16* dst = ys0 + ((size_t)t * BB + c * 16 + (lane >> 2)) * HH + n0 + (lane & 3) * 8;
        llc_store(dst, w.q[0]);
        llc_store(dst + 4, w.q[1]);
      }
      // off critical path: x-projection for t+1
      if (t + 1 < TT) {
#pragma unroll
        for (int j = 0; j < 2; ++j) { pacc[j][0] = (f32x4){0,0,0,0}; pacc[j][1] = (f32x4){0,0,0,0}; }
        const f16* xa = xt + ((size_t)(t + 1) * BB + c * 16 + fr) * II + kg * 8;
#pragma unroll
        for (int kf = 0; kf < 8; ++kf) {
          half8 a = *(const half8*)(xa + kf * 32);
          pacc[0][kf & 1] = __builtin_amdgcn_mfma_f32_16x16x32_f16(a, wbi[0][kf], pacc[0][kf & 1], 0, 0, 0);
          pacc[1][kf & 1] = __builtin_amdgcn_mfma_f32_16x16x32_f16(a, wbi[1][kf], pacc[1][kf & 1], 0, 0, 0);
        }
      }
    }
  } else {
    // =============== layer 1 ===============
    half8 wbi[2][16], wbh[2][16];
#pragma unroll
    for (int j = 0; j < 2; ++j) {
      const f16* wi = wih1 + (size_t)(n0 + j * 16 + fr) * HH + kg * 8;
#pragma unroll
      for (int kf = 0; kf < 16; ++kf) wbi[j][kf] = *(const half8*)(wi + kf * 32);
      const f16* wh = whh1 + (size_t)(n0 + j * 16 + fr) * HH + kg * 8;
#pragma unroll
      for (int kf = 0; kf < 16; ++kf) wbh[j][kf] = *(const half8*)(wh + kf * 32);
    }
    const float bias[2] = {bs1[n0 + fr], bs1[n0 + 16 + fr]};
    for (int t = 0; t < TT; ++t) {
      f32x4 acc[2][2] = {{{0,0,0,0},{0,0,0,0}},{{0,0,0,0},{0,0,0,0}}};
      {  // input from ys0[t] (lags layer 0 by >=1 step: usually ready)
        u64 q[32];
        load_valid16(ys0 + ((size_t)t * BB + c * 16 + fr) * HH + kg * 8, q);
#pragma unroll
        for (int kf = 0; kf < 16; ++kf) {
          U16 u; u.q[0] = q[2 * kf]; u.q[1] = q[2 * kf + 1];
          acc[0][kf & 1] = __builtin_amdgcn_mfma_f32_16x16x32_f16(u.h, wbi[0][kf], acc[0][kf & 1], 0, 0, 0);
          acc[1][kf & 1] = __builtin_amdgcn_mfma_f32_16x16x32_f16(u.h, wbi[1][kf], acc[1][kf & 1], 0, 0, 0);
        }
      }
      if (t > 0) {  // own recurrence h1[t-1]
        u64 q[32];
        load_valid16(h1h + ((size_t)(t - 1) * BB + c * 16 + fr) * HH + kg * 8, q);
#pragma unroll
        for (int kf = 0; kf < 16; ++kf) {
          U16 u; u.q[0] = q[2 * kf]; u.q[1] = q[2 * kf + 1];
          acc[0][kf & 1] = __builtin_amdgcn_mfma_f32_16x16x32_f16(u.h, wbh[0][kf], acc[0][kf & 1], 0, 0, 0);
          acc[1][kf & 1] = __builtin_amdgcn_mfma_f32_16x16x32_f16(u.h, wbh[1][kf], acc[1][kf & 1], 0, 0, 0);
        }
      }
#pragma unroll
      for (int j = 0; j < 2; ++j)
#pragma unroll
        for (int r = 0; r < 4; ++r)
          tile[(kg * 4 + r) * 32 + j * 16 + fr] =
              (f16)tanhf(acc[j][0][r] + acc[j][1][r] + bias[j]);
      {
        U16 w; w.h = *(const half8*)(tile + lane * 8);
        f16* dst = h1h + ((size_t)t * BB + c * 16 + (lane >> 2)) * HH + n0 + (lane & 3) * 8;
        llc_store(dst, w.q[0]);
        llc_store(dst + 4, w.q[1]);
      }
    }
    // ========= final FC: out[row][col0..col0+3] over FULL K=512 in 8 validated chunks =========
    {
      const int row = c * 16 + fr;        // batch row
      const int col0 = s * 16 + kg * 4;   // 4 output cols per lane
      const f16* hb = h1h + ((size_t)(TT - 1) * BB + row) * HH;
      float r0 = bfc[col0], r1 = bfc[col0 + 1], r2 = bfc[col0 + 2], r3 = bfc[col0 + 3];
      const float4* w0 = (const float4*)(wfc + (size_t)(col0 + 0) * HH);
      const float4* w1 = (const float4*)(wfc + (size_t)(col0 + 1) * HH);
      const float4* w2 = (const float4*)(wfc + (size_t)(col0 + 2) * HH);
      const float4* w3 = (const float4*)(wfc + (size_t)(col0 + 3) * HH);
      for (int ch = 0; ch < 8; ++ch) {        // 8 chunks x 16 u64 = 512 f16
        u64 q[16];
        for (int iter = 0; iter < 400000; ++iter) {
#pragma unroll
          for (int i = 0; i < 16; ++i) q[i] = llc_load(hb + (ch * 16 + i) * 4);
          int ok = 1;
#pragma unroll
          for (int i = 0; i < 16; ++i) ok &= (q[i] != SENT);
          if (__all(ok)) break;
        }
#pragma unroll
        for (int i = 0; i < 16; ++i) {
          U16 u; u.q[0] = q[i]; u.q[1] = 0;
          int bi = ch * 16 + i;
          float h0 = (float)u.h[0], h1 = (float)u.h[1], h2 = (float)u.h[2], h3 = (float)u.h[3];
          float4 a = w0[bi], b = w1[bi], cc = w2[bi], d = w3[bi];
          r0 += h0 * a.x + h1 * a.y + h2 * a.z + h3 * a.w;
          r1 += h0 * b.x + h1 * b.y + h2 * b.z + h3 * b.w;
          r2 += h0 * cc.x + h1 * cc.y + h2 * cc.z + h3 * cc.w;
          r3 += h0 * d.x + h1 * d.y + h2 * d.z + h3 * d.w;
        }
      }
      float4 o = {r0, r1, r2, r3};
      *(float4*)(out + (size_t)row * OO + col0) = o;
    }
  }
}

extern "C" void kernel_launch(void* const* d_in, const int* in_sizes, int n_in,
                              void* d_out, int out_size, void* d_ws, size_t ws_size,
                              hipStream_t stream) {
  const float* x    = (const float*)d_in[0];
  const float* wih0 = (const float*)d_in[1];
  const float* whh0 = (const float*)d_in[2];
  const float* bih0 = (const float*)d_in[3];
  const float* bhh0 = (const float*)d_in[4];
  const float* wih1 = (const float*)d_in[5];
  const float* whh1 = (const float*)d_in[6];
  const float* bih1 = (const float*)d_in[7];
  const float* bhh1 = (const float*)d_in[8];
  const float* wfc  = (const float*)d_in[9];
  const float* bfc  = (const float*)d_in[10];
  float* out = (float*)d_out;

  char* base = (char*)d_ws;
  size_t off = 0;
  auto take = [&](size_t bytes) {
    char* r = base + off;
    off = (off + bytes + 255) & ~(size_t)255;
    return r;
  };
  f16* xt      = (f16*)take((size_t)TT * BB * II * 2);   // 16.8 MB
  f16* ys0     = (f16*)take((size_t)TT * BB * HH * 2);   // 33.6 MB
  f16* h1h     = (f16*)take((size_t)TT * BB * HH * 2);   // 33.6 MB (contiguous with ys0)
  f16* fwih0   = (f16*)take((size_t)HH * II * 2);
  f16* fwhh0   = (f16*)take((size_t)HH * HH * 2);
  f16* fwih1   = (f16*)take((size_t)HH * HH * 2);
  f16* fwhh1   = (f16*)take((size_t)HH * HH * 2);
  float* bs0   = (float*)take(HH * 4);
  float* bs1   = (float*)take(HH * 4);
  (void)ws_size; (void)in_sizes; (void)n_in; (void)out_size;

  // sentinel-fill both history buffers (they are contiguous)
  size_t n_u64 = (size_t)2 * TT * BB * HH / 4;
  prep_sent<<<dim3(2048), dim3(256), 0, stream>>>((u64*)ys0, n_u64);
  prep_x<<<dim3(1024), dim3(256), 0, stream>>>(x, xt);
  prep_w<<<dim3(512), dim3(256), 0, stream>>>(wih0, whh0, wih1, whh1,
                                              bih0, bhh0, bih1, bhh1,
                                              fwih0, fwhh0, fwih1, fwhh1, bs0, bs1);

  rnn_seq<<<dim3(128), dim3(64), 0, stream>>>(xt, ys0, h1h,
                                              fwih0, fwhh0, fwih1, fwhh1,
                                              bs0, bs1, wfc, bfc, out);
}